// Round 15
// baseline (115.388 us; speedup 1.0000x reference)
//
#include <hip/hip_runtime.h>
#include <hip/hip_bf16.h>

#define B_SZ 2
#define S_LEN 2048
#define E_DIM 1024
#define NH 16
#define DH 64
#define M_ROWS (B_SZ * S_LEN) /* 4096 */
#define QB 128
#define KVB 64
#define NSLOT 34 /* partial slots per bh */

typedef __attribute__((ext_vector_type(8))) short short8;
typedef __attribute__((ext_vector_type(4))) float floatx4;
typedef __attribute__((ext_vector_type(4))) int intx4;

static __device__ __forceinline__ unsigned short f2bf(float f) {
    __hip_bfloat16 h = __float2bfloat16(f);
    return *reinterpret_cast<unsigned short*>(&h);
}
static __device__ __forceinline__ float bf2f(unsigned short u) {
    unsigned int v = ((unsigned int)u) << 16;
    return __builtin_bit_cast(float, v);
}
static __device__ __forceinline__ unsigned int pack2bf(float lo, float hi) {
    return (unsigned int)f2bf(lo) | ((unsigned int)f2bf(hi) << 16);
}

static __device__ __forceinline__ void gl2lds16(const void* g, void* l) {
    __builtin_amdgcn_global_load_lds((const __attribute__((address_space(1))) void*)g,
                                     (__attribute__((address_space(3))) void*)l, 16, 0, 0);
}

#define WAIT_VM0() asm volatile("s_waitcnt vmcnt(0)" ::: "memory")
#define WAIT_LGKM0() asm volatile("s_waitcnt lgkmcnt(0)" ::: "memory")

// ---------------- prep: fp32->bf16 convert (x) + 4 weight transposes, fused --------
__global__ __launch_bounds__(256) void prep(const float* __restrict__ x,
                                            unsigned short* __restrict__ Xb,
                                            const float* __restrict__ W0,
                                            const float* __restrict__ W1,
                                            const float* __restrict__ W2,
                                            const float* __restrict__ W3,
                                            unsigned short* __restrict__ T0,
                                            unsigned short* __restrict__ T1,
                                            unsigned short* __restrict__ T2,
                                            unsigned short* __restrict__ T3) {
    __shared__ float tile[32][33];
    int bid = blockIdx.x;
    int t = threadIdx.x;
    if (bid < 4096) { // cvt: 4096 blocks x 1024 elems
        int i = (bid * 256 + t) * 4;
        float4 v = *reinterpret_cast<const float4*>(x + i);
        ushort4 o;
        o.x = f2bf(v.x); o.y = f2bf(v.y); o.z = f2bf(v.z); o.w = f2bf(v.w);
        *reinterpret_cast<ushort4*>(Xb + i) = o;
        return;
    }
    int u = bid - 4096;
    int z = u >> 10, rest = u & 1023;
    int bx = (rest & 31) * 32, by = (rest >> 5) * 32;
    const float* W = (z == 0) ? W0 : (z == 1) ? W1 : (z == 2) ? W2 : W3;
    unsigned short* Wt = (z == 0) ? T0 : (z == 1) ? T1 : (z == 2) ? T2 : T3;
    int tx = t & 31, ty = t >> 5; // 32 x 8
#pragma unroll
    for (int i = 0; i < 32; i += 8)
        tile[ty + i][tx] = W[(size_t)(by + ty + i) * E_DIM + bx + tx];
    __syncthreads();
#pragma unroll
    for (int i = 0; i < 32; i += 8)
        Wt[(size_t)(bx + ty + i) * E_DIM + by + tx] = f2bf(tile[tx][ty + i]);
}

// Q scale folds 1/sqrt(D) AND log2(e) so attention can use raw v_exp_f32 (2^x).
#define QSCALE 0.18033688011112042f

// ---------------- fused QKV projection: 4-phase counted-vmcnt, 192x256 tiles --------
__global__ __launch_bounds__(512, 1) void gemm_qkv8(const unsigned short* __restrict__ Wcat,
                                                    const unsigned short* __restrict__ Xb,
                                                    const float* __restrict__ bq,
                                                    const float* __restrict__ bk,
                                                    const float* __restrict__ bv,
                                                    unsigned short* __restrict__ Qg,
                                                    unsigned short* __restrict__ Kg,
                                                    unsigned short* __restrict__ Vtg) {
    __shared__ __align__(16) char lds[2][57344]; // per buf: A 192x128B | B 256x128B

    int t = threadIdx.x;
    int b = blockIdx.x;
    int xcd = b & 7, ii = b >> 3;        // ii in [0,32)
    int it = (xcd & 3) * 4 + (ii >> 3);  // 0..15
    int jt = (xcd >> 2) * 8 + (ii & 7);  // 0..15
    int iBase = it * 192, jBase = jt << 8;

    int w = t >> 6, lane = t & 63;
    int lr = lane & 15, lh = lane >> 4;
    int wm = w >> 2, wn = w & 3; // 2m x 4n waves

    int srow = t >> 3;             // 0..63
    int scbx = ((t & 7) << 4) ^ ((srow & 7) << 4);

    const char* Ab = (const char*)Wcat;
    const char* Bb = (const char*)Xb;

    floatx4 acc[6][4];
#pragma unroll
    for (int i = 0; i < 6; i++)
#pragma unroll
        for (int j = 0; j < 4; j++) acc[i][j] = (floatx4){0.f, 0.f, 0.f, 0.f};

    auto stageA = [&](int buf, int kt) { // 192 rows = 3 passes
        int k0b = kt << 7;
#pragma unroll
        for (int c = 0; c < 3; c++)
            gl2lds16(Ab + (size_t)(iBase + c * 64 + srow) * 2048 + k0b + scbx,
                     &lds[buf][c * 8192 + t * 16]);
    };
    auto stageB = [&](int buf, int kt) { // 256 rows = 4 passes
        int k0b = kt << 7;
#pragma unroll
        for (int c = 0; c < 4; c++)
            gl2lds16(Bb + (size_t)(jBase + c * 64 + srow) * 2048 + k0b + scbx,
                     &lds[buf][24576 + c * 8192 + t * 16]);
    };

    short8 af[3][2], bf[4][2];
    auto rdA = [&](int buf, int qm) {
#pragma unroll
        for (int ml = 0; ml < 3; ml++)
#pragma unroll
            for (int ks = 0; ks < 2; ks++) {
                int row = wm * 96 + (qm * 3 + ml) * 16 + lr;
                af[ml][ks] = *reinterpret_cast<const short8*>(
                    &lds[buf][(row * 128 + ks * 64 + lh * 16) ^ ((row & 7) << 4)]);
            }
    };
    auto rdB = [&](int buf, int qn) {
#pragma unroll
        for (int nl = 0; nl < 2; nl++)
#pragma unroll
            for (int ks = 0; ks < 2; ks++) {
                int row = wn * 64 + (qn * 2 + nl) * 16 + lr;
                bf[qn * 2 + nl][ks] = *reinterpret_cast<const short8*>(
                    &lds[buf][24576 + ((row * 128 + ks * 64 + lh * 16) ^ ((row & 7) << 4))]);
            }
    };
    auto mfma12 = [&](int qm, int qn) {
        __builtin_amdgcn_s_setprio(1);
#pragma unroll
        for (int ml = 0; ml < 3; ml++)
#pragma unroll
            for (int nl = 0; nl < 2; nl++)
#pragma unroll
                for (int ks = 0; ks < 2; ks++)
                    acc[qm * 3 + ml][qn * 2 + nl] = __builtin_amdgcn_mfma_f32_16x16x32_bf16(
                        af[ml][ks], bf[qn * 2 + nl][ks], acc[qm * 3 + ml][qn * 2 + nl], 0, 0, 0);
        __builtin_amdgcn_s_setprio(0);
    };

    const int NT = 16; // K=1024 / 64
    stageA(0, 0);
    stageB(0, 0);
    WAIT_VM0();
    __builtin_amdgcn_s_barrier();

    for (int kt = 0; kt < NT; ++kt) {
        int cur = kt & 1, nxt = cur ^ 1;
        bool pf = (kt + 1 < NT);
        rdA(cur, 0);
        rdB(cur, 0);
        if (pf) stageA(nxt, kt + 1);
        __builtin_amdgcn_s_barrier();
        WAIT_LGKM0();
        __builtin_amdgcn_sched_barrier(0);
        mfma12(0, 0);
        __builtin_amdgcn_s_barrier();
        rdB(cur, 1);
        if (pf) stageB(nxt, kt + 1);
        __builtin_amdgcn_s_barrier();
        WAIT_LGKM0();
        __builtin_amdgcn_sched_barrier(0);
        mfma12(0, 1);
        __builtin_amdgcn_s_barrier();
        rdA(cur, 1);
        __builtin_amdgcn_s_barrier();
        WAIT_LGKM0();
        __builtin_amdgcn_sched_barrier(0);
        mfma12(1, 0);
        __builtin_amdgcn_s_barrier();
        if (pf) WAIT_VM0();
        __builtin_amdgcn_s_barrier();
        mfma12(1, 1);
        __builtin_amdgcn_s_barrier();
    }

    // ---------------- epilogue: per-m-frag (wsel uniform per 16-feature frag) -------
    __syncthreads(); // LDS free for reuse
    unsigned short* vt = reinterpret_cast<unsigned short*>(&lds[0][0] + w * 2560); // [16][80]

#pragma unroll
    for (int mi = 0; mi < 6; mi++) {
        int i0 = iBase + wm * 96 + mi * 16;
        int wsel = i0 >> 10;
        int im = i0 & 1023;
        const float* bias = (wsel == 0) ? bq : (wsel == 1) ? bk : bv;
        float4 bs = *reinterpret_cast<const float4*>(&bias[im + lh * 4]);
        if (wsel < 2) {
            unsigned short* O = wsel ? Kg : Qg;
            float scale = wsel ? 1.0f : QSCALE;
            int h = im >> 6, d0 = (im & 63) + lh * 4;
#pragma unroll
            for (int nf = 0; nf < 4; nf++) {
                int j = jBase + wn * 64 + nf * 16 + lr;
                int b_ = j >> 11, s = j & (S_LEN - 1);
                ushort4 pk;
                pk.x = f2bf((acc[mi][nf][0] + bs.x) * scale);
                pk.y = f2bf((acc[mi][nf][1] + bs.y) * scale);
                pk.z = f2bf((acc[mi][nf][2] + bs.z) * scale);
                pk.w = f2bf((acc[mi][nf][3] + bs.w) * scale);
                *reinterpret_cast<ushort4*>(
                    &O[((size_t)(b_ * NH + h) * S_LEN + s) * DH + d0]) = pk;
            }
        } else {
#pragma unroll
            for (int nf = 0; nf < 4; nf++)
#pragma unroll
                for (int r = 0; r < 4; r++) {
                    float bb = (r == 0) ? bs.x : (r == 1) ? bs.y : (r == 2) ? bs.z : bs.w;
                    vt[(lh * 4 + r) * 80 + nf * 16 + lr] = f2bf(acc[mi][nf][r] + bb);
                }
            WAIT_LGKM0();
            __builtin_amdgcn_sched_barrier(0);
            int h = im >> 6, d0 = im & 63;
#pragma unroll
            for (int p = 0; p < 2; p++) {
                int idx = p * 64 + lane;
                int dl = idx >> 3, sg = idx & 7;
                short8 vv = *reinterpret_cast<const short8*>(&vt[dl * 80 + sg * 8]);
                int j = jBase + wn * 64 + sg * 8;
                int b_ = j >> 11, s = j & (S_LEN - 1);
                *reinterpret_cast<short8*>(
                    &Vtg[((size_t)(b_ * NH + h) * DH + d0 + dl) * S_LEN + s]) = vv;
            }
            WAIT_LGKM0(); // vt reused next mi
            __builtin_amdgcn_sched_barrier(0);
        }
    }
}

// ---------------- output projection: counted-vmcnt, 128x128, C^T --------------------
__global__ __launch_bounds__(512, 2) void gemm_o8(const unsigned short* __restrict__ Wot,
                                                  const unsigned short* __restrict__ Og,
                                                  const float* __restrict__ bo,
                                                  float* __restrict__ out) {
    __shared__ __align__(16) char lds[2][2][16384]; // [buf][A=0/B=1][128 rows x 128B]

    int t = threadIdx.x;
    int b = blockIdx.x;
    int xcd = b & 7, ii = b >> 3;       // ii in [0,32)
    int it = ii & 7;
    int jt = (xcd << 2) | (ii >> 3);
    int iBase = it << 7, jBase = jt << 7;

    int w = t >> 6, lane = t & 63;
    int lr = lane & 15, lh = lane >> 4;
    int wm = w >> 2, wn = w & 3; // 2m x 4n

    int srow = t >> 3; // 0..63
    int scbx = ((t & 7) << 4) ^ ((srow & 7) << 4);

    const char* Ab = (const char*)Wot;
    const char* Bb = (const char*)Og;

    floatx4 acc[4][2];
#pragma unroll
    for (int i = 0; i < 4; i++)
#pragma unroll
        for (int j = 0; j < 2; j++) acc[i][j] = (floatx4){0.f, 0.f, 0.f, 0.f};

    auto stageA = [&](int buf, int kt) {
        int k0b = kt << 7;
#pragma unroll
        for (int c = 0; c < 2; c++)
            gl2lds16(Ab + (size_t)(iBase + c * 64 + srow) * 2048 + k0b + scbx,
                     &lds[buf][0][c * 8192 + t * 16]);
    };
    auto stageB = [&](int buf, int kt) {
        int k0b = kt << 7;
#pragma unroll
        for (int c = 0; c < 2; c++)
            gl2lds16(Bb + (size_t)(jBase + c * 64 + srow) * 2048 + k0b + scbx,
                     &lds[buf][1][c * 8192 + t * 16]);
    };

    short8 af[4][2], bf[2][2];
    auto rdA = [&](int buf, int qm) {
#pragma unroll
        for (int m2 = 0; m2 < 2; m2++)
#pragma unroll
            for (int ks = 0; ks < 2; ks++) {
                int mi = qm * 2 + m2;
                int row = wm * 64 + mi * 16 + lr;
                af[mi][ks] = *reinterpret_cast<const short8*>(
                    &lds[buf][0][(row * 128 + ks * 64 + lh * 16) ^ ((row & 7) << 4)]);
            }
    };
    auto rdB = [&](int buf) {
#pragma unroll
        for (int nf = 0; nf < 2; nf++)
#pragma unroll
            for (int ks = 0; ks < 2; ks++) {
                int row = wn * 32 + nf * 16 + lr;
                bf[nf][ks] = *reinterpret_cast<const short8*>(
                    &lds[buf][1][(row * 128 + ks * 64 + lh * 16) ^ ((row & 7) << 4)]);
            }
    };
    auto mfma8 = [&](int qm) {
        __builtin_amdgcn_s_setprio(1);
#pragma unroll
        for (int m2 = 0; m2 < 2; m2++)
#pragma unroll
            for (int nf = 0; nf < 2; nf++)
#pragma unroll
                for (int ks = 0; ks < 2; ks++) {
                    int mi = qm * 2 + m2;
                    acc[mi][nf] = __builtin_amdgcn_mfma_f32_16x16x32_bf16(
                        af[mi][ks], bf[nf][ks], acc[mi][nf], 0, 0, 0);
                }
        __builtin_amdgcn_s_setprio(0);
    };

    const int NT = 16; // K=1024 / 64
    stageA(0, 0);
    stageB(0, 0);
    WAIT_VM0();
    __builtin_amdgcn_s_barrier();

    for (int kt = 0; kt < NT; ++kt) {
        int cur = kt & 1, nxt = cur ^ 1;
        bool pf = (kt + 1 < NT);
        rdA(cur, 0);
        rdB(cur);
        if (pf) stageA(nxt, kt + 1);
        __builtin_amdgcn_s_barrier();
        WAIT_LGKM0();
        __builtin_amdgcn_sched_barrier(0);
        mfma8(0);
        __builtin_amdgcn_s_barrier();
        rdA(cur, 1);
        if (pf) stageB(nxt, kt + 1);
        __builtin_amdgcn_s_barrier();
        WAIT_LGKM0();
        __builtin_amdgcn_sched_barrier(0);
        mfma8(1);
        if (pf) WAIT_VM0();
        __builtin_amdgcn_s_barrier();
    }

#pragma unroll
    for (int mi = 0; mi < 4; mi++) {
        int i = iBase + wm * 64 + mi * 16 + lh * 4;
        float4 bs = *reinterpret_cast<const float4*>(&bo[i]);
#pragma unroll
        for (int nf = 0; nf < 2; nf++) {
            int j = jBase + wn * 32 + nf * 16 + lr;
            float4 o;
            o.x = acc[mi][nf][0] + bs.x;
            o.y = acc[mi][nf][1] + bs.y;
            o.z = acc[mi][nf][2] + bs.z;
            o.w = acc[mi][nf][3] + bs.w;
            *reinterpret_cast<float4*>(&out[(size_t)j * E_DIM + i]) = o;
        }
    }
}

// ---------------- attention: uniform 11-12-tile chunks, static segment tables -------
// Per bh the 272 causal tiles are cut into 24 equal chunks (11-12 tiles); a chunk is
// up to 3 (qb, kt-range) segments. Grid 768 = 3/CU, ALL blocks resident AND uniform
// duration -> no drain tail (round-14 occupancy was 24% from 2..12-tile spread).
static __device__ const signed char SEG_QB[24][3] = {
    {0,1,2},{2,3,4},{4,5,-1},{5,6,-1},{6,-1,-1},{7,-1,-1},{7,8,-1},{8,-1,-1},
    {9,-1,-1},{9,10,-1},{10,-1,-1},{10,11,-1},{11,-1,-1},{11,12,-1},{12,-1,-1},{12,-1,-1},
    {12,13,-1},{13,-1,-1},{13,14,-1},{14,-1,-1},{14,-1,-1},{14,15,-1},{15,-1,-1},{15,-1,-1}};
static __device__ const signed char SEG_LO[24][3] = {
    {0,0,0},{5,0,0},{2,0,0},{4,0,0},{3,0,0},{0,0,0},{12,0,0},{7,0,0},
    {0,0,0},{12,0,0},{3,0,0},{14,0,0},{4,0,0},{15,0,0},{2,0,0},{14,0,0},
    {25,0,0},{10,0,0},{22,0,0},{5,0,0},{16,0,0},{28,0,0},{9,0,0},{20,0,0}};
static __device__ const signed char SEG_HI[24][3] = { // exclusive
    {2,4,5},{6,8,2},{10,4,0},{12,3,0},{14,0,0},{12,0,0},{16,7,0},{18,0,0},
    {12,0,0},{20,3,0},{14,0,0},{22,4,0},{15,0,0},{24,2,0},{14,0,0},{25,0,0},
    {26,10,0},{22,0,0},{28,5,0},{16,0,0},{28,0,0},{30,9,0},{20,0,0},{32,0,0}};
static __device__ const signed char SEG_SLOT[24][3] = { // -1 = direct Og write
    {-1,-1,0},{1,-1,2},{3,4,0},{5,6,0},{7,0,0},{8,0,0},{9,10,0},{11,0,0},
    {12,0,0},{13,14,0},{15,0,0},{16,17,0},{18,0,0},{19,20,0},{21,0,0},{22,0,0},
    {23,24,0},{25,0,0},{26,27,0},{28,0,0},{29,0,0},{30,31,0},{32,0,0},{33,0,0}};

__global__ __launch_bounds__(256, 4) void attn_fwd(const unsigned short* __restrict__ Qg,
                                                   const unsigned short* __restrict__ Kg,
                                                   const unsigned short* __restrict__ Vtg,
                                                   unsigned short* __restrict__ Og,
                                                   unsigned short* __restrict__ OpA,
                                                   unsigned short* __restrict__ OpB,
                                                   float* __restrict__ lpart) {
    __shared__ __align__(16) char kt_lds[2][KVB * 128];
    __shared__ __align__(16) char vt_lds[2][KVB * 128];

    int bid = blockIdx.x;
    int xcd = bid & 7, ii = bid >> 3;  // [0,96)
    int bh = (xcd << 2) + ii / 24;
    int c = ii % 24;

    int w = threadIdx.x >> 6, lane = threadIdx.x & 63;
    int lr = lane & 15, lh = lane >> 4;

    const char* Kb = (const char*)(Kg + (size_t)bh * S_LEN * DH);
    const char* Vb = (const char*)(Vtg + (size_t)bh * DH * S_LEN);
    const unsigned short* Qb = Qg + (size_t)bh * S_LEN * DH;

    int wi0 = w * 2;
    int srow0 = wi0 * 8 + (lane >> 3);
    int scol = (lane & 7) << 4;

    auto stage = [&](int buf, int kt) { // K + V tiles, 2+2 x 1KB per wave
        int kv0 = kt * KVB;
#pragma unroll
        for (int i = 0; i < 2; ++i) {
            int row = srow0 + i * 8;
            int colb = scol ^ ((row & 7) << 4);
            gl2lds16(Kb + (size_t)(kv0 + row) * 128 + colb,
                     kt_lds[buf] + (wi0 + i) * 1024);
            gl2lds16(Vb + (size_t)row * (S_LEN * 2) + (size_t)kv0 * 2 + colb,
                     vt_lds[buf] + (wi0 + i) * 1024);
        }
    };

    for (int si = 0; si < 3; ++si) {
        int qb = SEG_QB[c][si];
        if (qb < 0) break;
        int klo = SEG_LO[c][si], khi = SEG_HI[c][si];
        int slot = SEG_SLOT[c][si];
        int q0 = qb * QB + w * 32;

        short8 aq[2][2];
#pragma unroll
        for (int m = 0; m < 2; m++)
#pragma unroll
            for (int ks = 0; ks < 2; ks++)
                aq[m][ks] = *reinterpret_cast<const short8*>(
                    Qb + (size_t)(q0 + m * 16 + lr) * DH + ks * 32 + lh * 8);

        floatx4 oacc[2][4];
        float lsum[2];
#pragma unroll
        for (int m = 0; m < 2; m++) {
#pragma unroll
            for (int dt = 0; dt < 4; dt++) oacc[m][dt] = (floatx4){0.f, 0.f, 0.f, 0.f};
            lsum[m] = 0.f;
        }

        stage(0, klo);
        __syncthreads();
        int buf = 0;

        for (int kt = klo; kt < khi; ++kt) {
            if (kt + 1 < khi) stage(buf ^ 1, kt + 1);
            int kv0 = kt * KVB;
            bool skip = (kv0 > q0 + 31);
            if (!skip) {
                const char* Kt = kt_lds[buf];
                const char* Vt = vt_lds[buf];
                // ---- QK^T (swapped: A=K, B=Q) -> S^T lane-local q rows ----
                floatx4 sacc[2][4];
#pragma unroll
                for (int m = 0; m < 2; m++)
#pragma unroll
                    for (int nt = 0; nt < 4; nt++) sacc[m][nt] = (floatx4){0.f, 0.f, 0.f, 0.f};
#pragma unroll
                for (int ks = 0; ks < 2; ks++)
#pragma unroll
                    for (int nt = 0; nt < 4; nt++) {
                        int row = nt * 16 + lr;
                        int addr = (row * 128 + ks * 64 + lh * 16) ^ ((row & 7) << 4);
                        short8 bk = *reinterpret_cast<const short8*>(Kt + addr);
#pragma unroll
                        for (int m = 0; m < 2; m++)
                            sacc[m][nt] = __builtin_amdgcn_mfma_f32_16x16x32_bf16(
                                bk, aq[m][ks], sacc[m][nt], 0, 0, 0);
                    }
                // ---- causal mask: kv = kv0+16nt+4lh+r, q = q0+16m+lr ----
                if (kv0 + KVB - 1 > q0) {
#pragma unroll
                    for (int m = 0; m < 2; m++)
#pragma unroll
                        for (int nt = 0; nt < 4; nt++)
#pragma unroll
                            for (int r = 0; r < 4; r++) {
                                int kcol = kv0 + nt * 16 + lh * 4 + r;
                                int qrow = q0 + m * 16 + lr;
                                if (kcol > qrow) sacc[m][nt][r] = -1e30f;
                            }
                }
                // ---- P = 2^S, pack to bf16 pairs ----
                unsigned int pk[2][4][2];
#pragma unroll
                for (int m = 0; m < 2; m++) {
                    float ls = 0.f;
#pragma unroll
                    for (int nt = 0; nt < 4; nt++) {
#pragma unroll
                        for (int r = 0; r < 4; r++) {
                            float p = __builtin_amdgcn_exp2f(sacc[m][nt][r]);
                            sacc[m][nt][r] = p;
                            ls += p;
                        }
                        pk[m][nt][0] = pack2bf(sacc[m][nt][0], sacc[m][nt][1]);
                        pk[m][nt][1] = pack2bf(sacc[m][nt][2], sacc[m][nt][3]);
                    }
                    lsum[m] += ls;
                }
                // ---- exchange -> A-frag; PV ----
                short8 pa[2][2];
                int hsel = lh >> 1;
#pragma unroll
                for (int m = 0; m < 2; m++)
#pragma unroll
                    for (int ks = 0; ks < 2; ks++) {
                        intx4 u;
#pragma unroll
                        for (int t4 = 0; t4 < 4; t4++) {
                            int src = lr + 32 * (lh & 1) + 16 * (t4 >> 1);
                            int r0 = __shfl((int)pk[m][2 * ks][t4 & 1], src);
                            int r1 = __shfl((int)pk[m][2 * ks + 1][t4 & 1], src);
                            u[t4] = hsel ? r1 : r0;
                        }
                        pa[m][ks] = __builtin_bit_cast(short8, u);
                    }
#pragma unroll
                for (int ks = 0; ks < 2; ks++)
#pragma unroll
                    for (int dt = 0; dt < 4; dt++) {
                        int row = dt * 16 + lr;
                        int addr = (row * 128 + ks * 64 + lh * 16) ^ ((row & 7) << 4);
                        short8 bv = *reinterpret_cast<const short8*>(Vt + addr);
#pragma unroll
                        for (int m = 0; m < 2; m++)
                            oacc[m][dt] = __builtin_amdgcn_mfma_f32_16x16x32_bf16(
                                pa[m][ks], bv, oacc[m][dt], 0, 0, 0);
                    }
            }
            __syncthreads();
            buf ^= 1;
        }

#pragma unroll
        for (int m = 0; m < 2; m++) {
            lsum[m] += __shfl_xor(lsum[m], 16);
            lsum[m] += __shfl_xor(lsum[m], 32);
        }

        if (slot >= 0) {
            int pi = bh * NSLOT + slot;
            unsigned short* Op = (pi < 896) ? OpA + (size_t)pi * (QB * DH)
                                            : OpB + (size_t)(pi - 896) * (QB * DH);
            float* lp = lpart + (size_t)pi * QB;
#pragma unroll
            for (int m = 0; m < 2; m++) {
                if (lh == 0) lp[w * 32 + m * 16 + lr] = lsum[m];
#pragma unroll
                for (int r = 0; r < 4; r++) {
                    int row = w * 32 + m * 16 + lh * 4 + r;
#pragma unroll
                    for (int dt = 0; dt < 4; dt++)
                        Op[row * DH + dt * 16 + lr] = f2bf(oacc[m][dt][r]);
                }
            }
        } else {
            int b_ = bh >> 4, h_ = bh & 15;
#pragma unroll
            for (int m = 0; m < 2; m++) {
#pragma unroll
                for (int r = 0; r < 4; r++) {
                    float lv = __shfl(lsum[m], lh * 4 + r);
                    float inv = 1.f / lv;
                    int srw = q0 + m * 16 + lh * 4 + r;
#pragma unroll
                    for (int dt = 0; dt < 4; dt++)
                        Og[((size_t)b_ * S_LEN + srw) * E_DIM + h_ * 64 + dt * 16 + lr] =
                            f2bf(oacc[m][dt][r] * inv);
                }
            }
        }
    }
}

// ---------------- merge split-qb partials, normalize, write Og ----------------------
static __device__ const signed char RQB[13] = {2, 4, 5, 6, 7, 8, 9, 10, 11, 12, 13, 14, 15};
static __device__ const signed char RS0[13] = {0, 2, 4, 6, 8, 10, 12, 14, 17, 20, 24, 27, 31};
static __device__ const signed char RC[13]  = {2, 2, 2, 2, 2, 2, 2, 3, 3, 4, 3, 4, 3};

__global__ __launch_bounds__(256) void attn_reduce(const unsigned short* __restrict__ OpA,
                                                   const unsigned short* __restrict__ OpB,
                                                   const float* __restrict__ lpart,
                                                   unsigned short* __restrict__ Og) {
    int bh = blockIdx.x; // 0..31
    int qy = blockIdx.y; // 0..12
    int qb = RQB[qy], s0 = RS0[qy], cnt = RC[qy];
    int pi0 = bh * NSLOT + s0;
    int t = threadIdx.x;
    int cg = t & 7, r0 = t >> 3;
    int b_ = bh >> 4, h_ = bh & 15;
    int qrow0 = qb * QB;
#pragma unroll
    for (int rr = 0; rr < 4; rr++) {
        int row = r0 + rr * 32;
        float ls = 0.f;
        float s[8] = {0.f, 0.f, 0.f, 0.f, 0.f, 0.f, 0.f, 0.f};
        for (int k = 0; k < cnt; k++) {
            int pi = pi0 + k;
            const unsigned short* P = (pi < 896) ? OpA + (size_t)pi * (QB * DH)
                                                 : OpB + (size_t)(pi - 896) * (QB * DH);
            ls += lpart[(size_t)pi * QB + row];
            short8 v = *reinterpret_cast<const short8*>(P + row * DH + cg * 8);
#pragma unroll
            for (int j = 0; j < 8; j++) s[j] += bf2f((unsigned short)v[j]);
        }
        float inv = 1.f / ls;
        short8 o;
#pragma unroll
        for (int j = 0; j < 8; j++) o[j] = (short)f2bf(s[j] * inv);
        *reinterpret_cast<short8*>(Og + ((size_t)b_ * S_LEN + qrow0 + row) * E_DIM +
                                   h_ * 64 + cg * 8) = o;
    }
}

extern "C" void kernel_launch(void* const* d_in, const int* in_sizes, int n_in,
                              void* d_out, int out_size, void* d_ws, size_t ws_size,
                              hipStream_t stream) {
    const float* x  = (const float*)d_in[0];
    const float* Wq = (const float*)d_in[1];
    const float* bq = (const float*)d_in[2];
    const float* Wk = (const float*)d_in[3];
    const float* bk = (const float*)d_in[4];
    const float* Wv = (const float*)d_in[5];
    const float* bv = (const float*)d_in[6];
    const float* Wo = (const float*)d_in[7];
    const float* bo = (const float*)d_in[8];
    float* out = (float*)d_out;

    const size_t NX = (size_t)M_ROWS * E_DIM; // 4M elems
    const size_t NW = (size_t)E_DIM * E_DIM;  // 1M elems
    unsigned short* ws  = (unsigned short*)d_ws;
    unsigned short* Xb  = ws;
    unsigned short* Wqt = Xb + NX;   // Wqt|Wkt|Wvt contiguous = Wcat [3072][1024]
    unsigned short* Wkt = Wqt + NW;
    unsigned short* Wvt = Wkt + NW;
    unsigned short* Wot = Wvt + NW;
    unsigned short* Qg  = Wot + NW;
    unsigned short* Kg  = Qg + NX;
    unsigned short* Vtg = Kg + NX;
    unsigned short* Og  = Vtg + NX;
    // Partial slots (16KB = 8192 u16 each), 1088 total (34/bh x 32 bh):
    //   slots 0..895   overlay Xb|Wqt|Wkt|Wvt (7M u16, dead after gemm_qkv8)
    //   slots 896..1087 + lpart after Og (proven region, rounds 3-11)
    unsigned short* OpA = Xb;
    unsigned short* OpB = Og + NX;
    float* lpart = (float*)(OpB + (size_t)192 * QB * DH);

    prep<<<dim3(8192), 256, 0, stream>>>(x, Xb, Wq, Wk, Wv, Wo, Wqt, Wkt, Wvt, Wot);

    gemm_qkv8<<<dim3(256), 512, 0, stream>>>(Wqt, Xb, bq, bk, bv, Qg, Kg, Vtg);

    attn_fwd<<<dim3(768), 256, 0, stream>>>(Qg, Kg, Vtg, Og, OpA, OpB, lpart);
    attn_reduce<<<dim3(32, 13), 256, 0, stream>>>(OpA, OpB, lpart, Og);

    gemm_o8<<<dim3(256), 512, 0, stream>>>(Wot, Og, bo, out);
}

// Round 16
// 103.155 us; speedup vs baseline: 1.1186x; 1.1186x over previous
//
#include <hip/hip_runtime.h>
#include <hip/hip_bf16.h>

#define B_SZ 2
#define S_LEN 2048
#define E_DIM 1024
#define NH 16
#define DH 64
#define M_ROWS (B_SZ * S_LEN) /* 4096 */
#define QB 128
#define KVB 64

typedef __attribute__((ext_vector_type(8))) short short8;
typedef __attribute__((ext_vector_type(4))) float floatx4;
typedef __attribute__((ext_vector_type(4))) int intx4;

static __device__ __forceinline__ unsigned short f2bf(float f) {
    __hip_bfloat16 h = __float2bfloat16(f);
    return *reinterpret_cast<unsigned short*>(&h);
}
static __device__ __forceinline__ float bf2f(unsigned short u) {
    unsigned int v = ((unsigned int)u) << 16;
    return __builtin_bit_cast(float, v);
}
static __device__ __forceinline__ unsigned int pack2bf(float lo, float hi) {
    return (unsigned int)f2bf(lo) | ((unsigned int)f2bf(hi) << 16);
}

static __device__ __forceinline__ void gl2lds16(const void* g, void* l) {
    __builtin_amdgcn_global_load_lds((const __attribute__((address_space(1))) void*)g,
                                     (__attribute__((address_space(3))) void*)l, 16, 0, 0);
}

#define WAIT_VM0() asm volatile("s_waitcnt vmcnt(0)" ::: "memory")
#define WAIT_LGKM0() asm volatile("s_waitcnt lgkmcnt(0)" ::: "memory")

// ---------------- prep: fp32->bf16 convert (x) + 4 weight transposes, fused --------
__global__ __launch_bounds__(256) void prep(const float* __restrict__ x,
                                            unsigned short* __restrict__ Xb,
                                            const float* __restrict__ W0,
                                            const float* __restrict__ W1,
                                            const float* __restrict__ W2,
                                            const float* __restrict__ W3,
                                            unsigned short* __restrict__ T0,
                                            unsigned short* __restrict__ T1,
                                            unsigned short* __restrict__ T2,
                                            unsigned short* __restrict__ T3) {
    __shared__ float tile[32][33];
    int bid = blockIdx.x;
    int t = threadIdx.x;
    if (bid < 4096) { // cvt: 4096 blocks x 1024 elems
        int i = (bid * 256 + t) * 4;
        float4 v = *reinterpret_cast<const float4*>(x + i);
        ushort4 o;
        o.x = f2bf(v.x); o.y = f2bf(v.y); o.z = f2bf(v.z); o.w = f2bf(v.w);
        *reinterpret_cast<ushort4*>(Xb + i) = o;
        return;
    }
    int u = bid - 4096;
    int z = u >> 10, rest = u & 1023;
    int bx = (rest & 31) * 32, by = (rest >> 5) * 32;
    const float* W = (z == 0) ? W0 : (z == 1) ? W1 : (z == 2) ? W2 : W3;
    unsigned short* Wt = (z == 0) ? T0 : (z == 1) ? T1 : (z == 2) ? T2 : T3;
    int tx = t & 31, ty = t >> 5; // 32 x 8
#pragma unroll
    for (int i = 0; i < 32; i += 8)
        tile[ty + i][tx] = W[(size_t)(by + ty + i) * E_DIM + bx + tx];
    __syncthreads();
#pragma unroll
    for (int i = 0; i < 32; i += 8)
        Wt[(size_t)(bx + ty + i) * E_DIM + by + tx] = f2bf(tile[tx][ty + i]);
}

// Q scale folds 1/sqrt(D) AND log2(e) so attention can use raw v_exp_f32 (2^x).
#define QSCALE 0.18033688011112042f

// ---------------- fused QKV projection: 4-phase counted-vmcnt, 192x256 tiles --------
// 16 i-tiles x 16 j-tiles = 256 blocks = exactly 1/CU. 512 thr / 8 waves (2m x 4n),
// per-wave 96x64 (6x4 frags), LDS 112KB dbuf.
__global__ __launch_bounds__(512, 1) void gemm_qkv8(const unsigned short* __restrict__ Wcat,
                                                    const unsigned short* __restrict__ Xb,
                                                    const float* __restrict__ bq,
                                                    const float* __restrict__ bk,
                                                    const float* __restrict__ bv,
                                                    unsigned short* __restrict__ Qg,
                                                    unsigned short* __restrict__ Kg,
                                                    unsigned short* __restrict__ Vtg) {
    __shared__ __align__(16) char lds[2][57344]; // per buf: A 192x128B | B 256x128B

    int t = threadIdx.x;
    int b = blockIdx.x;
    int xcd = b & 7, ii = b >> 3;        // ii in [0,32)
    int it = (xcd & 3) * 4 + (ii >> 3);  // 0..15
    int jt = (xcd >> 2) * 8 + (ii & 7);  // 0..15
    int iBase = it * 192, jBase = jt << 8;

    int w = t >> 6, lane = t & 63;
    int lr = lane & 15, lh = lane >> 4;
    int wm = w >> 2, wn = w & 3; // 2m x 4n waves

    int srow = t >> 3;             // 0..63
    int scbx = ((t & 7) << 4) ^ ((srow & 7) << 4);

    const char* Ab = (const char*)Wcat;
    const char* Bb = (const char*)Xb;

    floatx4 acc[6][4];
#pragma unroll
    for (int i = 0; i < 6; i++)
#pragma unroll
        for (int j = 0; j < 4; j++) acc[i][j] = (floatx4){0.f, 0.f, 0.f, 0.f};

    auto stageA = [&](int buf, int kt) { // 192 rows = 3 passes
        int k0b = kt << 7;
#pragma unroll
        for (int c = 0; c < 3; c++)
            gl2lds16(Ab + (size_t)(iBase + c * 64 + srow) * 2048 + k0b + scbx,
                     &lds[buf][c * 8192 + t * 16]);
    };
    auto stageB = [&](int buf, int kt) { // 256 rows = 4 passes
        int k0b = kt << 7;
#pragma unroll
        for (int c = 0; c < 4; c++)
            gl2lds16(Bb + (size_t)(jBase + c * 64 + srow) * 2048 + k0b + scbx,
                     &lds[buf][24576 + c * 8192 + t * 16]);
    };

    short8 af[3][2], bf[4][2];
    auto rdA = [&](int buf, int qm) {
#pragma unroll
        for (int ml = 0; ml < 3; ml++)
#pragma unroll
            for (int ks = 0; ks < 2; ks++) {
                int row = wm * 96 + (qm * 3 + ml) * 16 + lr;
                af[ml][ks] = *reinterpret_cast<const short8*>(
                    &lds[buf][(row * 128 + ks * 64 + lh * 16) ^ ((row & 7) << 4)]);
            }
    };
    auto rdB = [&](int buf, int qn) {
#pragma unroll
        for (int nl = 0; nl < 2; nl++)
#pragma unroll
            for (int ks = 0; ks < 2; ks++) {
                int row = wn * 64 + (qn * 2 + nl) * 16 + lr;
                bf[qn * 2 + nl][ks] = *reinterpret_cast<const short8*>(
                    &lds[buf][24576 + ((row * 128 + ks * 64 + lh * 16) ^ ((row & 7) << 4))]);
            }
    };
    auto mfma12 = [&](int qm, int qn) {
        __builtin_amdgcn_s_setprio(1);
#pragma unroll
        for (int ml = 0; ml < 3; ml++)
#pragma unroll
            for (int nl = 0; nl < 2; nl++)
#pragma unroll
                for (int ks = 0; ks < 2; ks++)
                    acc[qm * 3 + ml][qn * 2 + nl] = __builtin_amdgcn_mfma_f32_16x16x32_bf16(
                        af[ml][ks], bf[qn * 2 + nl][ks], acc[qm * 3 + ml][qn * 2 + nl], 0, 0, 0);
        __builtin_amdgcn_s_setprio(0);
    };

    const int NT = 16; // K=1024 / 64
    stageA(0, 0);
    stageB(0, 0);
    WAIT_VM0();
    __builtin_amdgcn_s_barrier();

    for (int kt = 0; kt < NT; ++kt) {
        int cur = kt & 1, nxt = cur ^ 1;
        bool pf = (kt + 1 < NT);
        rdA(cur, 0);
        rdB(cur, 0);
        if (pf) stageA(nxt, kt + 1);
        __builtin_amdgcn_s_barrier();
        WAIT_LGKM0();
        __builtin_amdgcn_sched_barrier(0);
        mfma12(0, 0);
        __builtin_amdgcn_s_barrier();
        rdB(cur, 1);
        if (pf) stageB(nxt, kt + 1);
        __builtin_amdgcn_s_barrier();
        WAIT_LGKM0();
        __builtin_amdgcn_sched_barrier(0);
        mfma12(0, 1);
        __builtin_amdgcn_s_barrier();
        rdA(cur, 1);
        __builtin_amdgcn_s_barrier();
        WAIT_LGKM0();
        __builtin_amdgcn_sched_barrier(0);
        mfma12(1, 0);
        __builtin_amdgcn_s_barrier();
        if (pf) WAIT_VM0();
        __builtin_amdgcn_s_barrier();
        mfma12(1, 1);
        __builtin_amdgcn_s_barrier();
    }

    // ---------------- epilogue: per-m-frag (wsel uniform per 16-feature frag) -------
    __syncthreads(); // LDS free for reuse
    unsigned short* vt = reinterpret_cast<unsigned short*>(&lds[0][0] + w * 2560); // [16][80]

#pragma unroll
    for (int mi = 0; mi < 6; mi++) {
        int i0 = iBase + wm * 96 + mi * 16;
        int wsel = i0 >> 10;
        int im = i0 & 1023;
        const float* bias = (wsel == 0) ? bq : (wsel == 1) ? bk : bv;
        float4 bs = *reinterpret_cast<const float4*>(&bias[im + lh * 4]);
        if (wsel < 2) {
            unsigned short* O = wsel ? Kg : Qg;
            float scale = wsel ? 1.0f : QSCALE;
            int h = im >> 6, d0 = (im & 63) + lh * 4;
#pragma unroll
            for (int nf = 0; nf < 4; nf++) {
                int j = jBase + wn * 64 + nf * 16 + lr;
                int b_ = j >> 11, s = j & (S_LEN - 1);
                ushort4 pk;
                pk.x = f2bf((acc[mi][nf][0] + bs.x) * scale);
                pk.y = f2bf((acc[mi][nf][1] + bs.y) * scale);
                pk.z = f2bf((acc[mi][nf][2] + bs.z) * scale);
                pk.w = f2bf((acc[mi][nf][3] + bs.w) * scale);
                *reinterpret_cast<ushort4*>(
                    &O[((size_t)(b_ * NH + h) * S_LEN + s) * DH + d0]) = pk;
            }
        } else {
#pragma unroll
            for (int nf = 0; nf < 4; nf++)
#pragma unroll
                for (int r = 0; r < 4; r++) {
                    float bb = (r == 0) ? bs.x : (r == 1) ? bs.y : (r == 2) ? bs.z : bs.w;
                    vt[(lh * 4 + r) * 80 + nf * 16 + lr] = f2bf(acc[mi][nf][r] + bb);
                }
            WAIT_LGKM0();
            __builtin_amdgcn_sched_barrier(0);
            int h = im >> 6, d0 = im & 63;
#pragma unroll
            for (int p = 0; p < 2; p++) {
                int idx = p * 64 + lane;
                int dl = idx >> 3, sg = idx & 7;
                short8 vv = *reinterpret_cast<const short8*>(&vt[dl * 80 + sg * 8]);
                int j = jBase + wn * 64 + sg * 8;
                int b_ = j >> 11, s = j & (S_LEN - 1);
                *reinterpret_cast<short8*>(
                    &Vtg[((size_t)(b_ * NH + h) * DH + d0 + dl) * S_LEN + s]) = vv;
            }
            WAIT_LGKM0(); // vt reused next mi
            __builtin_amdgcn_sched_barrier(0);
        }
    }
}

// ---------------- output projection: counted-vmcnt, 128x128, C^T --------------------
__global__ __launch_bounds__(512, 2) void gemm_o8(const unsigned short* __restrict__ Wot,
                                                  const unsigned short* __restrict__ Og,
                                                  const float* __restrict__ bo,
                                                  float* __restrict__ out) {
    __shared__ __align__(16) char lds[2][2][16384]; // [buf][A=0/B=1][128 rows x 128B]

    int t = threadIdx.x;
    int b = blockIdx.x;
    int xcd = b & 7, ii = b >> 3;       // ii in [0,32)
    int it = ii & 7;
    int jt = (xcd << 2) | (ii >> 3);
    int iBase = it << 7, jBase = jt << 7;

    int w = t >> 6, lane = t & 63;
    int lr = lane & 15, lh = lane >> 4;
    int wm = w >> 2, wn = w & 3; // 2m x 4n

    int srow = t >> 3; // 0..63
    int scbx = ((t & 7) << 4) ^ ((srow & 7) << 4);

    const char* Ab = (const char*)Wot;
    const char* Bb = (const char*)Og;

    floatx4 acc[4][2];
#pragma unroll
    for (int i = 0; i < 4; i++)
#pragma unroll
        for (int j = 0; j < 2; j++) acc[i][j] = (floatx4){0.f, 0.f, 0.f, 0.f};

    auto stageA = [&](int buf, int kt) {
        int k0b = kt << 7;
#pragma unroll
        for (int c = 0; c < 2; c++)
            gl2lds16(Ab + (size_t)(iBase + c * 64 + srow) * 2048 + k0b + scbx,
                     &lds[buf][0][c * 8192 + t * 16]);
    };
    auto stageB = [&](int buf, int kt) {
        int k0b = kt << 7;
#pragma unroll
        for (int c = 0; c < 2; c++)
            gl2lds16(Bb + (size_t)(jBase + c * 64 + srow) * 2048 + k0b + scbx,
                     &lds[buf][1][c * 8192 + t * 16]);
    };

    short8 af[4][2], bf[2][2];
    auto rdA = [&](int buf, int qm) {
#pragma unroll
        for (int m2 = 0; m2 < 2; m2++)
#pragma unroll
            for (int ks = 0; ks < 2; ks++) {
                int mi = qm * 2 + m2;
                int row = wm * 64 + mi * 16 + lr;
                af[mi][ks] = *reinterpret_cast<const short8*>(
                    &lds[buf][0][(row * 128 + ks * 64 + lh * 16) ^ ((row & 7) << 4)]);
            }
    };
    auto rdB = [&](int buf) {
#pragma unroll
        for (int nf = 0; nf < 2; nf++)
#pragma unroll
            for (int ks = 0; ks < 2; ks++) {
                int row = wn * 32 + nf * 16 + lr;
                bf[nf][ks] = *reinterpret_cast<const short8*>(
                    &lds[buf][1][(row * 128 + ks * 64 + lh * 16) ^ ((row & 7) << 4)]);
            }
    };
    auto mfma8 = [&](int qm) {
        __builtin_amdgcn_s_setprio(1);
#pragma unroll
        for (int m2 = 0; m2 < 2; m2++)
#pragma unroll
            for (int nf = 0; nf < 2; nf++)
#pragma unroll
                for (int ks = 0; ks < 2; ks++) {
                    int mi = qm * 2 + m2;
                    acc[mi][nf] = __builtin_amdgcn_mfma_f32_16x16x32_bf16(
                        af[mi][ks], bf[nf][ks], acc[mi][nf], 0, 0, 0);
                }
        __builtin_amdgcn_s_setprio(0);
    };

    const int NT = 16; // K=1024 / 64
    stageA(0, 0);
    stageB(0, 0);
    WAIT_VM0();
    __builtin_amdgcn_s_barrier();

    for (int kt = 0; kt < NT; ++kt) {
        int cur = kt & 1, nxt = cur ^ 1;
        bool pf = (kt + 1 < NT);
        rdA(cur, 0);
        rdB(cur);
        if (pf) stageA(nxt, kt + 1);
        __builtin_amdgcn_s_barrier();
        WAIT_LGKM0();
        __builtin_amdgcn_sched_barrier(0);
        mfma8(0);
        __builtin_amdgcn_s_barrier();
        rdA(cur, 1);
        if (pf) stageB(nxt, kt + 1);
        __builtin_amdgcn_s_barrier();
        WAIT_LGKM0();
        __builtin_amdgcn_sched_barrier(0);
        mfma8(1);
        if (pf) WAIT_VM0();
        __builtin_amdgcn_s_barrier();
    }

#pragma unroll
    for (int mi = 0; mi < 4; mi++) {
        int i = iBase + wm * 64 + mi * 16 + lh * 4;
        float4 bs = *reinterpret_cast<const float4*>(&bo[i]);
#pragma unroll
        for (int nf = 0; nf < 2; nf++) {
            int j = jBase + wn * 32 + nf * 16 + lr;
            float4 o;
            o.x = acc[mi][nf][0] + bs.x;
            o.y = acc[mi][nf][1] + bs.y;
            o.z = acc[mi][nf][2] + bs.z;
            o.w = acc[mi][nf][3] + bs.w;
            *reinterpret_cast<float4*>(&out[(size_t)j * E_DIM + i]) = o;
        }
    }
}

// ---------------- causal flash attention: swapped QK^T, in-register P ---------------
// (round-14 structure: 32KB LDS, 960-block balanced KV-split) + T5 setprio on MFMA.
__global__ __launch_bounds__(256, 4) void attn_fwd(const unsigned short* __restrict__ Qg,
                                                   const unsigned short* __restrict__ Kg,
                                                   const unsigned short* __restrict__ Vtg,
                                                   unsigned short* __restrict__ Og,
                                                   unsigned short* __restrict__ Opart,
                                                   float* __restrict__ lpart) {
    __shared__ __align__(16) char kt_lds[2][KVB * 128];
    __shared__ __align__(16) char vt_lds[2][KVB * 128];

    int bid = blockIdx.x;
    int xcd = bid & 7, ii = bid >> 3;  // [0,120)
    int bh = (xcd << 2) + ii / 30;
    int jj = 29 - (ii % 30);           // dispatch big-qb chunks first
    int qb, ch, c;
    if (jj < 6)        { qb = jj; ch = 0; c = 1; }
    else if (jj < 18)  { int u = jj - 6;  qb = 6 + (u >> 1); ch = u & 1; c = 2; }
    else               { int u = jj - 18; qb = 12 + u / 3;   ch = u % 3; c = 3; }
    int T = 2 * qb + 2;
    int kt_lo = ch * T / c;
    int kt_hi = (ch + 1) * T / c - 1;
    bool split = (c > 1);

    int w = threadIdx.x >> 6, lane = threadIdx.x & 63;
    int lr = lane & 15, lh = lane >> 4;
    int q0 = qb * QB + w * 32;

    const char* Kb = (const char*)(Kg + (size_t)bh * S_LEN * DH);
    const char* Vb = (const char*)(Vtg + (size_t)bh * DH * S_LEN);
    const unsigned short* Qb = Qg + (size_t)bh * S_LEN * DH;

    int wi0 = w * 2;
    int srow0 = wi0 * 8 + (lane >> 3);
    int scol = (lane & 7) << 4;

    auto stage = [&](int buf, int kt) { // K + V tiles, 2+2 x 1KB per wave
        int kv0 = kt * KVB;
#pragma unroll
        for (int i = 0; i < 2; ++i) {
            int row = srow0 + i * 8;
            int colb = scol ^ ((row & 7) << 4);
            gl2lds16(Kb + (size_t)(kv0 + row) * 128 + colb,
                     kt_lds[buf] + (wi0 + i) * 1024);
            gl2lds16(Vb + (size_t)row * (S_LEN * 2) + (size_t)kv0 * 2 + colb,
                     vt_lds[buf] + (wi0 + i) * 1024);
        }
    };

    short8 aq[2][2];
#pragma unroll
    for (int m = 0; m < 2; m++)
#pragma unroll
        for (int ks = 0; ks < 2; ks++)
            aq[m][ks] = *reinterpret_cast<const short8*>(
                Qb + (size_t)(q0 + m * 16 + lr) * DH + ks * 32 + lh * 8);

    floatx4 oacc[2][4];
    float lsum[2];
#pragma unroll
    for (int m = 0; m < 2; m++) {
#pragma unroll
        for (int dt = 0; dt < 4; dt++) oacc[m][dt] = (floatx4){0.f, 0.f, 0.f, 0.f};
        lsum[m] = 0.f;
    }

    stage(0, kt_lo);
    __syncthreads();
    int buf = 0;

    for (int kt = kt_lo; kt <= kt_hi; ++kt) {
        if (kt < kt_hi) stage(buf ^ 1, kt + 1);
        int kv0 = kt * KVB;
        bool skip = (kv0 > q0 + 31);
        if (!skip) {
            const char* Kt = kt_lds[buf];
            const char* Vt = vt_lds[buf];
            // ---- QK^T (swapped: A=K, B=Q) -> S^T: lane holds q=lr, k=16nt+4lh+r ----
            floatx4 sacc[2][4];
#pragma unroll
            for (int m = 0; m < 2; m++)
#pragma unroll
                for (int nt = 0; nt < 4; nt++) sacc[m][nt] = (floatx4){0.f, 0.f, 0.f, 0.f};
            __builtin_amdgcn_s_setprio(1);
#pragma unroll
            for (int ks = 0; ks < 2; ks++)
#pragma unroll
                for (int nt = 0; nt < 4; nt++) {
                    int row = nt * 16 + lr;
                    int addr = (row * 128 + ks * 64 + lh * 16) ^ ((row & 7) << 4);
                    short8 bk = *reinterpret_cast<const short8*>(Kt + addr);
#pragma unroll
                    for (int m = 0; m < 2; m++)
                        sacc[m][nt] = __builtin_amdgcn_mfma_f32_16x16x32_bf16(
                            bk, aq[m][ks], sacc[m][nt], 0, 0, 0);
                }
            __builtin_amdgcn_s_setprio(0);
            // ---- causal mask (diagonal band only): kv = kv0+16nt+4lh+r, q = q0+16m+lr
            if (kv0 + KVB - 1 > q0) {
#pragma unroll
                for (int m = 0; m < 2; m++)
#pragma unroll
                    for (int nt = 0; nt < 4; nt++)
#pragma unroll
                        for (int r = 0; r < 4; r++) {
                            int kcol = kv0 + nt * 16 + lh * 4 + r;
                            int qrow = q0 + m * 16 + lr;
                            if (kcol > qrow) sacc[m][nt][r] = -1e30f;
                        }
            }
            // ---- P = 2^S (lane-local rows), pack to bf16 pairs ----
            unsigned int pk[2][4][2];
#pragma unroll
            for (int m = 0; m < 2; m++) {
                float ls = 0.f;
#pragma unroll
                for (int nt = 0; nt < 4; nt++) {
#pragma unroll
                    for (int r = 0; r < 4; r++) {
                        float p = __builtin_amdgcn_exp2f(sacc[m][nt][r]);
                        sacc[m][nt][r] = p;
                        ls += p;
                    }
                    pk[m][nt][0] = pack2bf(sacc[m][nt][0], sacc[m][nt][1]);
                    pk[m][nt][1] = pack2bf(sacc[m][nt][2], sacc[m][nt][3]);
                }
                lsum[m] += ls;
            }
            // ---- exchange: build A-frag P[q=lr][k=32ks+8lh+e] from pk ----
            short8 pa[2][2];
            int hsel = lh >> 1;
#pragma unroll
            for (int m = 0; m < 2; m++)
#pragma unroll
                for (int ks = 0; ks < 2; ks++) {
                    intx4 u;
#pragma unroll
                    for (int t4 = 0; t4 < 4; t4++) {
                        int src = lr + 32 * (lh & 1) + 16 * (t4 >> 1);
                        int r0 = __shfl((int)pk[m][2 * ks][t4 & 1], src);
                        int r1 = __shfl((int)pk[m][2 * ks + 1][t4 & 1], src);
                        u[t4] = hsel ? r1 : r0;
                    }
                    pa[m][ks] = __builtin_bit_cast(short8, u);
                }
            // ---- PV (O row=q=4lh+r, col=d=lr) ----
            __builtin_amdgcn_s_setprio(1);
#pragma unroll
            for (int ks = 0; ks < 2; ks++)
#pragma unroll
                for (int dt = 0; dt < 4; dt++) {
                    int row = dt * 16 + lr;
                    int addr = (row * 128 + ks * 64 + lh * 16) ^ ((row & 7) << 4);
                    short8 bv = *reinterpret_cast<const short8*>(Vt + addr);
#pragma unroll
                    for (int m = 0; m < 2; m++)
                        oacc[m][dt] = __builtin_amdgcn_mfma_f32_16x16x32_bf16(
                            pa[m][ks], bv, oacc[m][dt], 0, 0, 0);
                }
            __builtin_amdgcn_s_setprio(0);
        }
        __syncthreads();
        buf ^= 1;
    }

#pragma unroll
    for (int m = 0; m < 2; m++) {
        lsum[m] += __shfl_xor(lsum[m], 16);
        lsum[m] += __shfl_xor(lsum[m], 32);
    }

    if (split) {
        int base = (qb < 12) ? (qb - 6) * 2 : 12 + (qb - 12) * 3;
        int pi = bh * 24 + base + ch;
        unsigned short* Op = Opart + (size_t)pi * (QB * DH);
        float* lp = lpart + (size_t)pi * QB;
#pragma unroll
        for (int m = 0; m < 2; m++) {
            if (lh == 0) lp[w * 32 + m * 16 + lr] = lsum[m];
#pragma unroll
            for (int r = 0; r < 4; r++) {
                int row = w * 32 + m * 16 + lh * 4 + r;
#pragma unroll
                for (int dt = 0; dt < 4; dt++)
                    Op[row * DH + dt * 16 + lr] = f2bf(oacc[m][dt][r]);
            }
        }
    } else {
        int b_ = bh >> 4, h_ = bh & 15;
#pragma unroll
        for (int m = 0; m < 2; m++) {
#pragma unroll
            for (int r = 0; r < 4; r++) {
                float lv = __shfl(lsum[m], lh * 4 + r);
                float inv = 1.f / lv;
                int srow = q0 + m * 16 + lh * 4 + r;
#pragma unroll
                for (int dt = 0; dt < 4; dt++)
                    Og[((size_t)b_ * S_LEN + srow) * E_DIM + h_ * 64 + dt * 16 + lr] =
                        f2bf(oacc[m][dt][r] * inv);
            }
        }
    }
}

// ---------------- merge KV-split partials (2 or 3 chunks), normalize, write Og ------
__global__ __launch_bounds__(256) void attn_reduce(const unsigned short* __restrict__ Opart,
                                                   const float* __restrict__ lpart,
                                                   unsigned short* __restrict__ Og) {
    int bh = blockIdx.x;      // 0..31
    int qb = 6 + blockIdx.y;  // 6..15
    int c = (qb < 12) ? 2 : 3;
    int base = (qb < 12) ? (qb - 6) * 2 : 12 + (qb - 12) * 3;
    int pi0 = bh * 24 + base;
    const unsigned short* P0 = Opart + (size_t)pi0 * (QB * DH);
    const float* l0 = lpart + (size_t)pi0 * QB;
    int t = threadIdx.x;
    int cg = t & 7, r0 = t >> 3;
    int b_ = bh >> 4, h_ = bh & 15;
    int qrow0 = qb * QB;
#pragma unroll
    for (int rr = 0; rr < 4; rr++) {
        int row = r0 + rr * 32;
        float ls = l0[row] + l0[QB + row];
        if (c == 3) ls += l0[2 * QB + row];
        float inv = 1.f / ls;
        short8 v0 = *reinterpret_cast<const short8*>(P0 + row * DH + cg * 8);
        short8 v1 = *reinterpret_cast<const short8*>(P0 + QB * DH + row * DH + cg * 8);
        float s[8];
#pragma unroll
        for (int j = 0; j < 8; j++)
            s[j] = bf2f((unsigned short)v0[j]) + bf2f((unsigned short)v1[j]);
        if (c == 3) {
            short8 v2 = *reinterpret_cast<const short8*>(P0 + 2 * QB * DH + row * DH + cg * 8);
#pragma unroll
            for (int j = 0; j < 8; j++) s[j] += bf2f((unsigned short)v2[j]);
        }
        short8 o;
#pragma unroll
        for (int j = 0; j < 8; j++) o[j] = (short)f2bf(s[j] * inv);
        *reinterpret_cast<short8*>(Og + ((size_t)b_ * S_LEN + qrow0 + row) * E_DIM +
                                   h_ * 64 + cg * 8) = o;
    }
}

extern "C" void kernel_launch(void* const* d_in, const int* in_sizes, int n_in,
                              void* d_out, int out_size, void* d_ws, size_t ws_size,
                              hipStream_t stream) {
    const float* x  = (const float*)d_in[0];
    const float* Wq = (const float*)d_in[1];
    const float* bq = (const float*)d_in[2];
    const float* Wk = (const float*)d_in[3];
    const float* bk = (const float*)d_in[4];
    const float* Wv = (const float*)d_in[5];
    const float* bv = (const float*)d_in[6];
    const float* Wo = (const float*)d_in[7];
    const float* bo = (const float*)d_in[8];
    float* out = (float*)d_out;

    const size_t NX = (size_t)M_ROWS * E_DIM; // 4M elems
    const size_t NW = (size_t)E_DIM * E_DIM;  // 1M elems
    unsigned short* ws  = (unsigned short*)d_ws;
    unsigned short* Xb  = ws;
    unsigned short* Wqt = Xb + NX;   // Wqt|Wkt|Wvt contiguous = Wcat [3072][1024]
    unsigned short* Wkt = Wqt + NW;
    unsigned short* Wvt = Wkt + NW;
    unsigned short* Wot = Wvt + NW;
    unsigned short* Qg  = Wot + NW;
    unsigned short* Kg  = Qg + NX;
    unsigned short* Vtg = Kg + NX;
    unsigned short* Og  = Vtg + NX;
    // Partials OVERLAY the Xb/Wqt/Wkt/Wvt region (dead after gemm_qkv8):
    unsigned short* Opart = Xb;
    float* lpart = (float*)(Opart + (size_t)32 * 24 * QB * DH);

    prep<<<dim3(8192), 256, 0, stream>>>(x, Xb, Wq, Wk, Wv, Wo, Wqt, Wkt, Wvt, Wot);

    gemm_qkv8<<<dim3(256), 512, 0, stream>>>(Wqt, Xb, bq, bk, bv, Qg, Kg, Vtg);

    attn_fwd<<<dim3(960), 256, 0, stream>>>(Qg, Kg, Vtg, Og, Opart, lpart);
    attn_reduce<<<dim3(B_SZ * NH, 10), 256, 0, stream>>>(Opart, lpart, Og);

    gemm_o8<<<dim3(256), 512, 0, stream>>>(Wot, Og, bo, out);
}